// Round 15
// baseline (117.154 us; speedup 1.0000x reference)
//
#include <hip/hip_runtime.h>
#include <hip/hip_bf16.h>

#define NB   16
#define CINC 64
#define COUTC 64
#define NV   25
#define TLEN 512
#define KK   3
#define TKK  3

typedef short short8 __attribute__((ext_vector_type(8)));
typedef float f32x16 __attribute__((ext_vector_type(16)));

#define NWT3BLK (NV * 9)   // 225 weight-prep blocks
#define XS_BYTES 16640     // 130 rows * 128 B bf16 slab

__device__ __forceinline__ unsigned pack_bf16(float lo, float hi) {
  __hip_bfloat16 l = __float2bfloat16(lo);
  __hip_bfloat16 h = __float2bfloat16(hi);
  unsigned short ul = *reinterpret_cast<unsigned short*>(&l);
  unsigned short uh = *reinterpret_cast<unsigned short*>(&h);
  return (unsigned)ul | ((unsigned)uh << 16);
}

// ================= prep: Wt3 only (xT eliminated — fused into main) =========
// Wt3[blk=(v*3+k)*3+kt][oslab][ks][lane][e] bf16, mask folded in.
__global__ __launch_bounds__(256) void prep_wt3(
    const float* __restrict__ W, const unsigned char* __restrict__ mask_raw,
    __hip_bfloat16* __restrict__ Wt3) {
  int blk = blockIdx.x;            // v*9 + k*3 + kt
  int v = blk / 9, kkt = blk % 9, k = kkt / 3, kt = kkt % 3;
  const int* mi = (const int*)mask_raw;
  int ok = 1;
  for (int i = 0; i < 18; ++i) {
    int m = mi[i];
    if (m != 0 && m != 1) ok = 0;
  }
  int m = ok ? mi[v * KK + k] : (int)(mask_raw[v * KK + k] != 0);
  const float* Wv = W + (size_t)v * COUTC * CINC * 9;
  __hip_bfloat16* dst = Wt3 + (size_t)blk * 4096;
  for (int i = threadIdx.x; i < 4096; i += 256) {
    int e     = i & 7;
    int lane  = (i >> 3) & 63;
    int ks    = (i >> 9) & 3;
    int oslab = i >> 11;
    int o = oslab * 32 + (lane & 31);
    int c = ks * 16 + 8 * (lane >> 5) + e;
    float val = m ? Wv[(o * CINC + c) * 9 + k * 3 + kt] : 0.f;
    dst[i] = __float2bfloat16(val);
  }
}

// Main (fused): block = 64 o x 128 t for (tchunk, n, v). Reads x fp32 direct,
// transposes+casts in-kernel (reg-staged, swizzled ds_write_b32), R10's
// counted-vmcnt ladder. 3 LDS buffers -> no WAR across phases, one barrier
// per phase. Eliminates the 14 us xT prep kernel and 52 MB of HBM traffic.
__global__ __launch_bounds__(256, 3) void lcn_fused(
    const float* __restrict__ x,
    const __hip_bfloat16* __restrict__ Wt3,
    const float* __restrict__ bias,
    const int* __restrict__ idx,
    float* __restrict__ out) {
  __shared__ char xs0[XS_BYTES], xs1[XS_BYTES], xs2[XS_BYTES];  // 49,920 B

  const int tb   = blockIdx.x * 128;
  const int n    = blockIdx.y;
  const int v    = blockIdx.z;
  const int tid  = threadIdx.x;
  const int lane = tid & 63;
  const int wave = tid >> 6;
  const int os   = wave & 1;     // this wave's o-slab
  const int th   = wave >> 1;    // this wave's 64-t half
  const int hi   = lane >> 5;
  const int l31  = lane & 31;
  const int c2   = tid & 31;     // staging: c-pair index
  const int slot = tid >> 5;     // staging: t-quad slot (0..7)
  const int cA   = 2 * c2, cB = 2 * c2 + 1;

  const int vk0 = idx[v * KK + 0];
  const int vk1 = idx[v * KK + 1];
  const int vk2 = idx[v * KK + 2];

#define LOAD_A(DST, KIDX)                                                     \
  {                                                                           \
    const short8* wb = (const short8*)Wt3 +                                   \
        ((size_t)((v * KK + (KIDX)) * TKK) * 2 + os) * 256 + lane;            \
    _Pragma("unroll") for (int kt = 0; kt < TKK; ++kt)                        \
      _Pragma("unroll") for (int ks = 0; ks < 4; ++ks)                        \
        DST[kt * 4 + ks] = wb[kt * 512 + (ks << 6)];                          \
  }

  // 10 uniform float4 loads per slab per thread (clamped q/t => static count)
#define LOAD_SLAB(SA, SB, VK)                                                 \
  {                                                                           \
    const float* pA = x + (((size_t)n * CINC + cA) * NV + (VK)) * TLEN;       \
    const float* pB = x + (((size_t)n * CINC + cB) * NV + (VK)) * TLEN;       \
    _Pragma("unroll") for (int j = 0; j < 5; ++j) {                           \
      int q = slot + 8 * j;                                                   \
      if (q > 33) q = 33;                                                     \
      int gt = tb - 4 + 4 * q;                                                \
      gt = gt < 0 ? 0 : (gt > TLEN - 4 ? TLEN - 4 : gt);                      \
      SA[j] = *(const float4*)(pA + gt);                                      \
      SB[j] = *(const float4*)(pB + gt);                                      \
    }                                                                         \
  }

  // convert + swizzled ds_write_b32; duplicate clamped writes are same-value
  // (benign); halo rows zeroed at t-extremes.
#define WRITE_SLAB(SA, SB, DST)                                               \
  {                                                                           \
    _Pragma("unroll") for (int j = 0; j < 5; ++j) {                           \
      int q = slot + 8 * j;                                                   \
      if (q < 34) {                                                           \
        int gt = tb - 4 + 4 * q;                                              \
        gt = gt < 0 ? 0 : (gt > TLEN - 4 ? TLEN - 4 : gt);                    \
        float ea[4] = {SA[j].x, SA[j].y, SA[j].z, SA[j].w};                   \
        float eb[4] = {SB[j].x, SB[j].y, SB[j].z, SB[j].w};                   \
        _Pragma("unroll") for (int e = 0; e < 4; ++e) {                       \
          int r = gt + e - tb + 1;                                            \
          if (r >= 0 && r < 130) {                                            \
            int ad = (r * 128 + c2 * 4) ^ ((r & 7) << 4);                     \
            *(unsigned*)((DST) + ad) = pack_bf16(ea[e], eb[e]);               \
          }                                                                   \
        }                                                                     \
      }                                                                       \
    }                                                                         \
    if (tb == 0 && slot == 0) *(unsigned*)((DST) + c2 * 4) = 0u;              \
    if (tb == TLEN - 128 && slot == 1)                                        \
      *(unsigned*)((DST) + ((129 * 128 + c2 * 4) ^ 16)) = 0u;                 \
  }

#define COMPUTE_K(CB, A)                                                      \
  _Pragma("unroll") for (int kt = 0; kt < TKK; ++kt) {                        \
    {                                                                         \
      const int r  = th * 64 + l31 + kt;                                      \
      const int sw = (r & 7) << 4;                                            \
      const int co = hi * 16;                                                 \
      const char* bp = (CB) + r * 128;                                        \
      _Pragma("unroll") for (int ks = 0; ks < 4; ++ks) {                      \
        short8 bfr = *(const short8*)(bp + ((co + 32 * ks) ^ sw));            \
        acc0 = __builtin_amdgcn_mfma_f32_32x32x16_bf16(A[kt * 4 + ks], bfr,   \
                                                       acc0, 0, 0, 0);        \
      }                                                                       \
    }                                                                         \
    {                                                                         \
      const int r  = th * 64 + 32 + l31 + kt;                                 \
      const int sw = (r & 7) << 4;                                            \
      const int co = hi * 16;                                                 \
      const char* bp = (CB) + r * 128;                                        \
      _Pragma("unroll") for (int ks = 0; ks < 4; ++ks) {                      \
        short8 bfr = *(const short8*)(bp + ((co + 32 * ks) ^ sw));            \
        acc1 = __builtin_amdgcn_mfma_f32_32x32x16_bf16(A[kt * 4 + ks], bfr,   \
                                                       acc1, 0, 0, 0);        \
      }                                                                       \
    }                                                                         \
  }

  short8 aP[12], aQ[12];
  float4 sA[5], sB[5], tA[5], tB[5];

  // ---- prologue: A0(12) | S0(10) | S1(10) ----
  LOAD_A(aP, 0)
  __builtin_amdgcn_sched_barrier(0);
  LOAD_SLAB(sA, sB, vk0)
  __builtin_amdgcn_sched_barrier(0);
  LOAD_SLAB(tA, tB, vk1)
  __builtin_amdgcn_sched_barrier(0);
  asm volatile("s_waitcnt vmcnt(10)" ::: "memory");   // A0+S0 done (S1 left)
  WRITE_SLAB(sA, sB, xs0)
  asm volatile("s_waitcnt lgkmcnt(0)" ::: "memory");
  __builtin_amdgcn_s_barrier();
  __builtin_amdgcn_sched_barrier(0);

  f32x16 acc0 = {}, acc1 = {};

  // ---- k0: compute xs0 w/ A0; prefetch A1; then land S1 ----
  LOAD_A(aQ, 1)                                       // queue: S1(10)+A1(12)
  __builtin_amdgcn_sched_barrier(0);
  COMPUTE_K(xs0, aP)
  asm volatile("s_waitcnt vmcnt(12)" ::: "memory");   // S1 done (A1 left)
  WRITE_SLAB(tA, tB, xs1)
  asm volatile("s_waitcnt lgkmcnt(0)" ::: "memory");
  __builtin_amdgcn_s_barrier();
  __builtin_amdgcn_sched_barrier(0);

  // ---- k1: issue S2 + A2; compute xs1 w/ A1; land S2 ----
  LOAD_SLAB(sA, sB, vk2)                              // S2 reuses sA/sB
  __builtin_amdgcn_sched_barrier(0);
  LOAD_A(aP, 2)                                       // queue: S2(10)+A2(12)
  __builtin_amdgcn_sched_barrier(0);
  COMPUTE_K(xs1, aQ)
  asm volatile("s_waitcnt vmcnt(12)" ::: "memory");   // S2 done (A2 left)
  WRITE_SLAB(sA, sB, xs2)
  asm volatile("s_waitcnt lgkmcnt(0)" ::: "memory");
  __builtin_amdgcn_s_barrier();
  __builtin_amdgcn_sched_barrier(0);

  // ---- k2: compute xs2 w/ A2 (issued a full phase ago) ----
  COMPUTE_K(xs2, aP)

#undef LOAD_A
#undef LOAD_SLAB
#undef WRITE_SLAB
#undef COMPUTE_K

  // epilogue: D col(t)=lane&31, row(o)=(reg&3)+8*(reg>>2)+4*(lane>>5)
  const float* bv = bias + v * COUTC;
#pragma unroll
  for (int s = 0; s < 2; ++s) {
    const f32x16& acc = s ? acc1 : acc0;
    const int t = tb + th * 64 + s * 32 + l31;
#pragma unroll
    for (int reg = 0; reg < 16; ++reg) {
      int o = os * 32 + 4 * hi + (reg & 3) + 8 * (reg >> 2);
      out[(((size_t)n * COUTC + o) * NV + v) * TLEN + t] = acc[reg] + bv[o];
    }
  }
}

// ================= FALLBACK PATH (round-1 fp32, known-good) =================
__global__ void prep_mask_kernel(const int* __restrict__ mask_raw,
                                 int* __restrict__ mask_out) {
  __shared__ int fmt;
  if (threadIdx.x == 0) {
    int ok = 1;
    for (int i = 0; i < 18; ++i) {
      int m = mask_raw[i];
      if (m != 0 && m != 1) ok = 0;
    }
    fmt = ok;
  }
  __syncthreads();
  int i = threadIdx.x;
  if (i < NV * KK) {
    int m;
    if (fmt) m = mask_raw[i];
    else     m = (((const unsigned char*)mask_raw)[i] != 0) ? 1 : 0;
    mask_out[i] = m;
  }
}

__global__ void prep_wt_kernel(const float* __restrict__ W,
                               float* __restrict__ Wt) {
  int v   = blockIdx.x / 9;
  int kkt = blockIdx.x % 9;
  const float* Wv = W + (size_t)v * COUTC * CINC * 9;
  float* dst = Wt + (size_t)blockIdx.x * (CINC * COUTC);
  for (int i = threadIdx.x; i < CINC * COUTC; i += 256) {
    int c = i >> 6;
    int o = i & 63;
    dst[i] = Wv[(o * CINC + c) * 9 + kkt];
  }
}

__global__ __launch_bounds__(256, 4) void lcn_main(
    const float* __restrict__ x, const float* __restrict__ Wt,
    const float* __restrict__ b, const int* __restrict__ idx,
    const int* __restrict__ maskn, float* __restrict__ out) {
  __shared__ float xsf[CINC][66];
  __shared__ float wsh[CINC][COUTC];
  const int tb  = blockIdx.x * 64;
  const int v   = blockIdx.y;
  const int n   = blockIdx.z;
  const int tid = threadIdx.x;
  const int t0  = tid & 63;
  const int og  = tid >> 6;
  float acc[16];
#pragma unroll
  for (int j = 0; j < 16; ++j) acc[j] = 0.f;
  for (int k = 0; k < KK; ++k) {
    const int vk = idx[v * KK + k];
    const int mk = maskn[v * KK + k];
    __syncthreads();
    for (int i = tid; i < CINC * 66; i += 256) {
      int c  = i / 66;
      int tt = i - c * 66;
      int gt = tb - 1 + tt;
      float val = 0.f;
      if (mk && gt >= 0 && gt < TLEN)
        val = x[(((size_t)n * CINC + c) * NV + vk) * TLEN + gt];
      xsf[c][tt] = val;
    }
    for (int kt = 0; kt < TKK; ++kt) {
      __syncthreads();
      const float4* src =
          (const float4*)(Wt + ((size_t)(v * KK + k) * TKK + kt) * (CINC * COUTC));
      for (int i = tid; i < CINC * COUTC / 4; i += 256)
        ((float4*)wsh)[i] = src[i];
      __syncthreads();
#pragma unroll 4
      for (int c = 0; c < CINC; ++c) {
        float xv = xsf[c][t0 + kt];
        const float4* wrow = (const float4*)&wsh[c][og * 16];
#pragma unroll
        for (int j4 = 0; j4 < 4; ++j4) {
          float4 wv = wrow[j4];
          acc[j4 * 4 + 0] = fmaf(wv.x, xv, acc[j4 * 4 + 0]);
          acc[j4 * 4 + 1] = fmaf(wv.y, xv, acc[j4 * 4 + 1]);
          acc[j4 * 4 + 2] = fmaf(wv.z, xv, acc[j4 * 4 + 2]);
          acc[j4 * 4 + 3] = fmaf(wv.w, xv, acc[j4 * 4 + 3]);
        }
      }
    }
  }
#pragma unroll
  for (int j = 0; j < 16; ++j) {
    int o = og * 16 + j;
    out[(((size_t)n * COUTC + o) * NV + v) * TLEN + tb + t0] =
        acc[j] + b[v * COUTC + o];
  }
}

extern "C" void kernel_launch(void* const* d_in, const int* in_sizes, int n_in,
                              void* d_out, int out_size, void* d_ws, size_t ws_size,
                              hipStream_t stream) {
  const float* x    = (const float*)d_in[0];
  const float* W    = (const float*)d_in[1];
  const float* b    = (const float*)d_in[2];
  const int*   idx  = (const int*)d_in[3];
  const void*  mask = (const void*)d_in[4];
  float* out = (float*)d_out;

  // ws: [0,512) maskn (fallback) | Wt3 1.84MB | guard
  const size_t WT3_BYTES = (size_t)NV * 9 * 4096 * sizeof(__hip_bfloat16);
  const size_t NEED      = 512 + WT3_BYTES + 2048;

  if (ws_size >= NEED) {
    __hip_bfloat16* Wt3 = (__hip_bfloat16*)((char*)d_ws + 512);
    hipLaunchKernelGGL(prep_wt3, dim3(NWT3BLK), dim3(256), 0, stream,
                       W, (const unsigned char*)mask, Wt3);
    hipLaunchKernelGGL(lcn_fused, dim3(TLEN / 128, NB, NV), dim3(256), 0,
                       stream, x, Wt3, b, idx, out);
  } else {
    int*   maskn = (int*)d_ws;
    float* Wt    = (float*)((char*)d_ws + 512);
    hipLaunchKernelGGL(prep_mask_kernel, dim3(1), dim3(128), 0, stream,
                       (const int*)mask, maskn);
    hipLaunchKernelGGL(prep_wt_kernel, dim3(NV * KK * TKK), dim3(256), 0, stream,
                       W, Wt);
    hipLaunchKernelGGL(lcn_main, dim3(TLEN / 64, NV, NB), dim3(256), 0, stream,
                       x, Wt, b, idx, maskn, out);
  }
}

// Round 16
// 62.040 us; speedup vs baseline: 1.8884x; 1.8884x over previous
//
#include <hip/hip_runtime.h>
#include <hip/hip_bf16.h>

#define NB   16
#define CINC 64
#define COUTC 64
#define NV   25
#define TLEN 512
#define KK   3
#define TKK  3

typedef short short8 __attribute__((ext_vector_type(8)));
typedef float f32x16 __attribute__((ext_vector_type(16)));

#define NWT3BLK (NV * 9)   // 225 weight-prep blocks
#define XS_BYTES 16640     // 130 rows * 128 B bf16 slab

__device__ __forceinline__ unsigned pack_bf16(float lo, float hi) {
  __hip_bfloat16 l = __float2bfloat16(lo);
  __hip_bfloat16 h = __float2bfloat16(hi);
  unsigned short ul = *reinterpret_cast<unsigned short*>(&l);
  unsigned short uh = *reinterpret_cast<unsigned short*>(&h);
  return (unsigned)ul | ((unsigned)uh << 16);
}

// ================= prep: Wt3 only (xT eliminated — fused into main) =========
__global__ __launch_bounds__(256) void prep_wt3(
    const float* __restrict__ W, const unsigned char* __restrict__ mask_raw,
    __hip_bfloat16* __restrict__ Wt3) {
  int blk = blockIdx.x;            // v*9 + k*3 + kt
  int v = blk / 9, kkt = blk % 9, k = kkt / 3, kt = kkt % 3;
  const int* mi = (const int*)mask_raw;
  int ok = 1;
  for (int i = 0; i < 18; ++i) {
    int m = mi[i];
    if (m != 0 && m != 1) ok = 0;
  }
  int m = ok ? mi[v * KK + k] : (int)(mask_raw[v * KK + k] != 0);
  const float* Wv = W + (size_t)v * COUTC * CINC * 9;
  __hip_bfloat16* dst = Wt3 + (size_t)blk * 4096;
  for (int i = threadIdx.x; i < 4096; i += 256) {
    int e     = i & 7;
    int lane  = (i >> 3) & 63;
    int ks    = (i >> 9) & 3;
    int oslab = i >> 11;
    int o = oslab * 32 + (lane & 31);
    int c = ks * 16 + 8 * (lane >> 5) + e;
    float val = m ? Wv[(o * CINC + c) * 9 + k * 3 + kt] : 0.f;
    dst[i] = __float2bfloat16(val);
  }
}

// Main (fused): identical to R15 except __launch_bounds__(256,2) — R15's 130us
// was pure spill traffic from the (256,3) VGPR cap (~168) vs ~190 live regs
// (VGPR_Count=84, WRITE 169MB, FETCH 150MB). At (256,2) the live set fits:
// 2 blocks/CU, 8 waves/CU, zero scratch. Gate: WRITE back to ~52MB.
__global__ __launch_bounds__(256, 2) void lcn_fused(
    const float* __restrict__ x,
    const __hip_bfloat16* __restrict__ Wt3,
    const float* __restrict__ bias,
    const int* __restrict__ idx,
    float* __restrict__ out) {
  __shared__ char xs0[XS_BYTES], xs1[XS_BYTES], xs2[XS_BYTES];  // 49,920 B

  const int tb   = blockIdx.x * 128;
  const int n    = blockIdx.y;
  const int v    = blockIdx.z;
  const int tid  = threadIdx.x;
  const int lane = tid & 63;
  const int wave = tid >> 6;
  const int os   = wave & 1;     // this wave's o-slab
  const int th   = wave >> 1;    // this wave's 64-t half
  const int hi   = lane >> 5;
  const int l31  = lane & 31;
  const int c2   = tid & 31;     // staging: c-pair index
  const int slot = tid >> 5;     // staging: t-quad slot (0..7)
  const int cA   = 2 * c2, cB = 2 * c2 + 1;

  const int vk0 = idx[v * KK + 0];
  const int vk1 = idx[v * KK + 1];
  const int vk2 = idx[v * KK + 2];

#define LOAD_A(DST, KIDX)                                                     \
  {                                                                           \
    const short8* wb = (const short8*)Wt3 +                                   \
        ((size_t)((v * KK + (KIDX)) * TKK) * 2 + os) * 256 + lane;            \
    _Pragma("unroll") for (int kt = 0; kt < TKK; ++kt)                        \
      _Pragma("unroll") for (int ks = 0; ks < 4; ++ks)                        \
        DST[kt * 4 + ks] = wb[kt * 512 + (ks << 6)];                          \
  }

#define LOAD_SLAB(SA, SB, VK)                                                 \
  {                                                                           \
    const float* pA = x + (((size_t)n * CINC + cA) * NV + (VK)) * TLEN;       \
    const float* pB = x + (((size_t)n * CINC + cB) * NV + (VK)) * TLEN;       \
    _Pragma("unroll") for (int j = 0; j < 5; ++j) {                           \
      int q = slot + 8 * j;                                                   \
      if (q > 33) q = 33;                                                     \
      int gt = tb - 4 + 4 * q;                                                \
      gt = gt < 0 ? 0 : (gt > TLEN - 4 ? TLEN - 4 : gt);                      \
      SA[j] = *(const float4*)(pA + gt);                                      \
      SB[j] = *(const float4*)(pB + gt);                                      \
    }                                                                         \
  }

#define WRITE_SLAB(SA, SB, DST)                                               \
  {                                                                           \
    _Pragma("unroll") for (int j = 0; j < 5; ++j) {                           \
      int q = slot + 8 * j;                                                   \
      if (q < 34) {                                                           \
        int gt = tb - 4 + 4 * q;                                              \
        gt = gt < 0 ? 0 : (gt > TLEN - 4 ? TLEN - 4 : gt);                    \
        float ea[4] = {SA[j].x, SA[j].y, SA[j].z, SA[j].w};                   \
        float eb[4] = {SB[j].x, SB[j].y, SB[j].z, SB[j].w};                   \
        _Pragma("unroll") for (int e = 0; e < 4; ++e) {                       \
          int r = gt + e - tb + 1;                                            \
          if (r >= 0 && r < 130) {                                            \
            int ad = (r * 128 + c2 * 4) ^ ((r & 7) << 4);                     \
            *(unsigned*)((DST) + ad) = pack_bf16(ea[e], eb[e]);               \
          }                                                                   \
        }                                                                     \
      }                                                                       \
    }                                                                         \
    if (tb == 0 && slot == 0) *(unsigned*)((DST) + c2 * 4) = 0u;              \
    if (tb == TLEN - 128 && slot == 1)                                        \
      *(unsigned*)((DST) + ((129 * 128 + c2 * 4) ^ 16)) = 0u;                 \
  }

#define COMPUTE_K(CB, A)                                                      \
  _Pragma("unroll") for (int kt = 0; kt < TKK; ++kt) {                        \
    {                                                                         \
      const int r  = th * 64 + l31 + kt;                                      \
      const int sw = (r & 7) << 4;                                            \
      const int co = hi * 16;                                                 \
      const char* bp = (CB) + r * 128;                                        \
      _Pragma("unroll") for (int ks = 0; ks < 4; ++ks) {                      \
        short8 bfr = *(const short8*)(bp + ((co + 32 * ks) ^ sw));            \
        acc0 = __builtin_amdgcn_mfma_f32_32x32x16_bf16(A[kt * 4 + ks], bfr,   \
                                                       acc0, 0, 0, 0);        \
      }                                                                       \
    }                                                                         \
    {                                                                         \
      const int r  = th * 64 + 32 + l31 + kt;                                 \
      const int sw = (r & 7) << 4;                                            \
      const int co = hi * 16;                                                 \
      const char* bp = (CB) + r * 128;                                        \
      _Pragma("unroll") for (int ks = 0; ks < 4; ++ks) {                      \
        short8 bfr = *(const short8*)(bp + ((co + 32 * ks) ^ sw));            \
        acc1 = __builtin_amdgcn_mfma_f32_32x32x16_bf16(A[kt * 4 + ks], bfr,   \
                                                       acc1, 0, 0, 0);        \
      }                                                                       \
    }                                                                         \
  }

  short8 aP[12], aQ[12];
  float4 sA[5], sB[5], tA[5], tB[5];

  // ---- prologue: A0(12) | S0(10) | S1(10) ----
  LOAD_A(aP, 0)
  __builtin_amdgcn_sched_barrier(0);
  LOAD_SLAB(sA, sB, vk0)
  __builtin_amdgcn_sched_barrier(0);
  LOAD_SLAB(tA, tB, vk1)
  __builtin_amdgcn_sched_barrier(0);
  asm volatile("s_waitcnt vmcnt(10)" ::: "memory");   // A0+S0 done (S1 left)
  WRITE_SLAB(sA, sB, xs0)
  asm volatile("s_waitcnt lgkmcnt(0)" ::: "memory");
  __builtin_amdgcn_s_barrier();
  __builtin_amdgcn_sched_barrier(0);

  f32x16 acc0 = {}, acc1 = {};

  // ---- k0: compute xs0 w/ A0; prefetch A1; then land S1 ----
  LOAD_A(aQ, 1)                                       // queue: S1(10)+A1(12)
  __builtin_amdgcn_sched_barrier(0);
  COMPUTE_K(xs0, aP)
  asm volatile("s_waitcnt vmcnt(12)" ::: "memory");   // S1 done (A1 left)
  WRITE_SLAB(tA, tB, xs1)
  asm volatile("s_waitcnt lgkmcnt(0)" ::: "memory");
  __builtin_amdgcn_s_barrier();
  __builtin_amdgcn_sched_barrier(0);

  // ---- k1: issue S2 + A2; compute xs1 w/ A1; land S2 ----
  LOAD_SLAB(sA, sB, vk2)                              // S2 reuses sA/sB
  __builtin_amdgcn_sched_barrier(0);
  LOAD_A(aP, 2)                                       // queue: S2(10)+A2(12)
  __builtin_amdgcn_sched_barrier(0);
  COMPUTE_K(xs1, aQ)
  asm volatile("s_waitcnt vmcnt(12)" ::: "memory");   // S2 done (A2 left)
  WRITE_SLAB(sA, sB, xs2)
  asm volatile("s_waitcnt lgkmcnt(0)" ::: "memory");
  __builtin_amdgcn_s_barrier();
  __builtin_amdgcn_sched_barrier(0);

  // ---- k2: compute xs2 w/ A2 (issued a full phase ago) ----
  COMPUTE_K(xs2, aP)

#undef LOAD_A
#undef LOAD_SLAB
#undef WRITE_SLAB
#undef COMPUTE_K

  // epilogue: D col(t)=lane&31, row(o)=(reg&3)+8*(reg>>2)+4*(lane>>5)
  const float* bv = bias + v * COUTC;
#pragma unroll
  for (int s = 0; s < 2; ++s) {
    const f32x16& acc = s ? acc1 : acc0;
    const int t = tb + th * 64 + s * 32 + l31;
#pragma unroll
    for (int reg = 0; reg < 16; ++reg) {
      int o = os * 32 + 4 * hi + (reg & 3) + 8 * (reg >> 2);
      out[(((size_t)n * COUTC + o) * NV + v) * TLEN + t] = acc[reg] + bv[o];
    }
  }
}

// ================= FALLBACK PATH (round-1 fp32, known-good) =================
__global__ void prep_mask_kernel(const int* __restrict__ mask_raw,
                                 int* __restrict__ mask_out) {
  __shared__ int fmt;
  if (threadIdx.x == 0) {
    int ok = 1;
    for (int i = 0; i < 18; ++i) {
      int m = mask_raw[i];
      if (m != 0 && m != 1) ok = 0;
    }
    fmt = ok;
  }
  __syncthreads();
  int i = threadIdx.x;
  if (i < NV * KK) {
    int m;
    if (fmt) m = mask_raw[i];
    else     m = (((const unsigned char*)mask_raw)[i] != 0) ? 1 : 0;
    mask_out[i] = m;
  }
}

__global__ void prep_wt_kernel(const float* __restrict__ W,
                               float* __restrict__ Wt) {
  int v   = blockIdx.x / 9;
  int kkt = blockIdx.x % 9;
  const float* Wv = W + (size_t)v * COUTC * CINC * 9;
  float* dst = Wt + (size_t)blockIdx.x * (CINC * COUTC);
  for (int i = threadIdx.x; i < CINC * COUTC; i += 256) {
    int c = i >> 6;
    int o = i & 63;
    dst[i] = Wv[(o * CINC + c) * 9 + kkt];
  }
}

__global__ __launch_bounds__(256, 4) void lcn_main(
    const float* __restrict__ x, const float* __restrict__ Wt,
    const float* __restrict__ b, const int* __restrict__ idx,
    const int* __restrict__ maskn, float* __restrict__ out) {
  __shared__ float xsf[CINC][66];
  __shared__ float wsh[CINC][COUTC];
  const int tb  = blockIdx.x * 64;
  const int v   = blockIdx.y;
  const int n   = blockIdx.z;
  const int tid = threadIdx.x;
  const int t0  = tid & 63;
  const int og  = tid >> 6;
  float acc[16];
#pragma unroll
  for (int j = 0; j < 16; ++j) acc[j] = 0.f;
  for (int k = 0; k < KK; ++k) {
    const int vk = idx[v * KK + k];
    const int mk = maskn[v * KK + k];
    __syncthreads();
    for (int i = tid; i < CINC * 66; i += 256) {
      int c  = i / 66;
      int tt = i - c * 66;
      int gt = tb - 1 + tt;
      float val = 0.f;
      if (mk && gt >= 0 && gt < TLEN)
        val = x[(((size_t)n * CINC + c) * NV + vk) * TLEN + gt];
      xsf[c][tt] = val;
    }
    for (int kt = 0; kt < TKK; ++kt) {
      __syncthreads();
      const float4* src =
          (const float4*)(Wt + ((size_t)(v * KK + k) * TKK + kt) * (CINC * COUTC));
      for (int i = tid; i < CINC * COUTC / 4; i += 256)
        ((float4*)wsh)[i] = src[i];
      __syncthreads();
#pragma unroll 4
      for (int c = 0; c < CINC; ++c) {
        float xv = xsf[c][t0 + kt];
        const float4* wrow = (const float4*)&wsh[c][og * 16];
#pragma unroll
        for (int j4 = 0; j4 < 4; ++j4) {
          float4 wv = wrow[j4];
          acc[j4 * 4 + 0] = fmaf(wv.x, xv, acc[j4 * 4 + 0]);
          acc[j4 * 4 + 1] = fmaf(wv.y, xv, acc[j4 * 4 + 1]);
          acc[j4 * 4 + 2] = fmaf(wv.z, xv, acc[j4 * 4 + 2]);
          acc[j4 * 4 + 3] = fmaf(wv.w, xv, acc[j4 * 4 + 3]);
        }
      }
    }
  }
#pragma unroll
  for (int j = 0; j < 16; ++j) {
    int o = og * 16 + j;
    out[(((size_t)n * COUTC + o) * NV + v) * TLEN + tb + t0] =
        acc[j] + b[v * COUTC + o];
  }
}

extern "C" void kernel_launch(void* const* d_in, const int* in_sizes, int n_in,
                              void* d_out, int out_size, void* d_ws, size_t ws_size,
                              hipStream_t stream) {
  const float* x    = (const float*)d_in[0];
  const float* W    = (const float*)d_in[1];
  const float* b    = (const float*)d_in[2];
  const int*   idx  = (const int*)d_in[3];
  const void*  mask = (const void*)d_in[4];
  float* out = (float*)d_out;

  // ws: [0,512) maskn (fallback) | Wt3 1.84MB | guard
  const size_t WT3_BYTES = (size_t)NV * 9 * 4096 * sizeof(__hip_bfloat16);
  const size_t NEED      = 512 + WT3_BYTES + 2048;

  if (ws_size >= NEED) {
    __hip_bfloat16* Wt3 = (__hip_bfloat16*)((char*)d_ws + 512);
    hipLaunchKernelGGL(prep_wt3, dim3(NWT3BLK), dim3(256), 0, stream,
                       W, (const unsigned char*)mask, Wt3);
    hipLaunchKernelGGL(lcn_fused, dim3(TLEN / 128, NB, NV), dim3(256), 0,
                       stream, x, Wt3, b, idx, out);
  } else {
    int*   maskn = (int*)d_ws;
    float* Wt    = (float*)((char*)d_ws + 512);
    hipLaunchKernelGGL(prep_mask_kernel, dim3(1), dim3(128), 0, stream,
                       (const int*)mask, maskn);
    hipLaunchKernelGGL(prep_wt_kernel, dim3(NV * KK * TKK), dim3(256), 0, stream,
                       W, Wt);
    hipLaunchKernelGGL(lcn_main, dim3(TLEN / 64, NV, NB), dim3(256), 0, stream,
                       x, Wt, b, idx, maskn, out);
  }
}

// Round 17
// 46.638 us; speedup vs baseline: 2.5120x; 1.3303x over previous
//
#include <hip/hip_runtime.h>
#include <hip/hip_bf16.h>

#define NB   16
#define CINC 64
#define COUTC 64
#define NV   25
#define TLEN 512
#define KK   3
#define TKK  3

typedef short short8 __attribute__((ext_vector_type(8)));
typedef float f32x4  __attribute__((ext_vector_type(4)));
typedef float f32x16 __attribute__((ext_vector_type(16)));

#define XT_ROWS 514        // padded: row 0 = t=-1 (zero), rows 1..512 = t, row 513 = t=512 (zero)
#define XS_STRIDE 17408    // 17 x 1KB stage ops; used bytes = 130*128 = 16640
#define NWT3BLK (NV * 9)   // 225 weight-prep blocks

__device__ __forceinline__ unsigned pack_bf16(float lo, float hi) {
  __hip_bfloat16 l = __float2bfloat16(lo);
  __hip_bfloat16 h = __float2bfloat16(hi);
  unsigned short ul = *reinterpret_cast<unsigned short*>(&l);
  unsigned short uh = *reinterpret_cast<unsigned short*>(&h);
  return (unsigned)ul | ((unsigned)uh << 16);
}

// ================= fused prep: Wt3 (blocks 0..224) + padded xT (rest) ========
__global__ __launch_bounds__(256) void prep_all(
    const float* __restrict__ x, const float* __restrict__ W,
    const unsigned char* __restrict__ mask_raw,
    __hip_bfloat16* __restrict__ Wt3, __hip_bfloat16* __restrict__ xT) {
  __shared__ float ts[64][65];
  int bid = blockIdx.x;
  if (bid < NWT3BLK) {
    int blk = bid;                 // v*9 + k*3 + kt
    int v = blk / 9, kkt = blk % 9, k = kkt / 3, kt = kkt % 3;
    const int* mi = (const int*)mask_raw;
    int ok = 1;
    for (int i = 0; i < 18; ++i) {
      int m = mi[i];
      if (m != 0 && m != 1) ok = 0;
    }
    int m = ok ? mi[v * KK + k] : (int)(mask_raw[v * KK + k] != 0);
    const float* Wv = W + (size_t)v * COUTC * CINC * 9;
    __hip_bfloat16* dst = Wt3 + (size_t)blk * 4096;
    for (int i = threadIdx.x; i < 4096; i += 256) {
      int e     = i & 7;
      int lane  = (i >> 3) & 63;
      int ks    = (i >> 9) & 3;
      int oslab = i >> 11;
      int o = oslab * 32 + (lane & 31);
      int c = ks * 16 + 8 * (lane >> 5) + e;
      float val = m ? Wv[(o * CINC + c) * 9 + k * 3 + kt] : 0.f;
      dst[i] = __float2bfloat16(val);
    }
    return;
  }
  bid -= NWT3BLK;
  const int tb = (bid & 7) * 64;
  const int vn = bid >> 3;
  const int v  = vn % NV;
  const int n  = vn / NV;
  const int tid = threadIdx.x;
  for (int i = tid; i < 1024; i += 256) {
    int c = i >> 4, tq = (i & 15) * 4;
    float4 val = *(const float4*)(x + (((size_t)n * CINC + c) * NV + v) * TLEN + tb + tq);
    ts[c][tq + 0] = val.x;
    ts[c][tq + 1] = val.y;
    ts[c][tq + 2] = val.z;
    ts[c][tq + 3] = val.w;
  }
  __syncthreads();
  unsigned* base = (unsigned*)(xT + ((size_t)(n * NV + v) * XT_ROWS) * CINC);
  for (int i = tid; i < 2048; i += 256) {
    int c2 = i & 31, t = i >> 5;
    base[(tb + 1 + t) * 32 + c2] = pack_bf16(ts[2 * c2][t], ts[2 * c2 + 1][t]);
  }
  if (tb == 0 && tid < 32) base[tid] = 0u;
  if (tb == TLEN - 64 && tid < 32) base[513 * 32 + tid] = 0u;
}

__device__ __forceinline__ const char* slab_base(const __hip_bfloat16* xT,
                                                 int n, int vk, int tb) {
  return (const char*)xT + ((size_t)(n * NV + vk) * XT_ROWS + tb) * 128;
}

// Main: R10/R14 verified optimum (46.6-46.8 us total, reproducible).
// Counted-vmcnt schedule, raw s_barrier, A-prefetch ladder, one 128-t phase
// per block, 1600 blocks. R11-R16 established: XCD swizzle, 2-phase
// amortization, deep store-in-queue ladders, and prep-fusion are all null
// or negative (counter-verified causes). This is the final kernel.
__global__ __launch_bounds__(256, 3) void lcn_mfma32(
    const __hip_bfloat16* __restrict__ xT,
    const __hip_bfloat16* __restrict__ Wt3,
    const float* __restrict__ bias,
    const int* __restrict__ idx,
    float* __restrict__ out) {
  __shared__ char xs[KK][XS_STRIDE];   // 52,224 B
  __shared__ char xs_dummy[1024];      // dummy-op sink (never read)

  const int tb   = blockIdx.x * 128;
  const int n    = blockIdx.y;
  const int v    = blockIdx.z;
  const int tid  = threadIdx.x;
  const int lane = tid & 63;
  const int wave = tid >> 6;
  const int os   = wave & 1;     // this wave's o-slab
  const int th   = wave >> 1;    // this wave's 64-t half
  const int hi   = lane >> 5;
  const int l31  = lane & 31;

#define LOAD_A(DST, KIDX)                                                     \
  {                                                                           \
    const short8* wb = (const short8*)Wt3 +                                   \
        ((size_t)((v * KK + (KIDX)) * TKK) * 2 + os) * 256 + lane;            \
    _Pragma("unroll") for (int kt = 0; kt < TKK; ++kt)                        \
      _Pragma("unroll") for (int ks = 0; ks < 4; ++ks)                        \
        DST[kt * 4 + ks] = wb[kt * 512 + (ks << 6)];                          \
  }

#define COMPUTE_K(CB, A)                                                      \
  _Pragma("unroll") for (int kt = 0; kt < TKK; ++kt) {                        \
    {                                                                         \
      const int r  = th * 64 + l31 + kt;                                      \
      const int sw = (r & 7) << 4;                                            \
      const int co = hi * 16;                                                 \
      const char* bp = (CB) + r * 128;                                        \
      _Pragma("unroll") for (int ks = 0; ks < 4; ++ks) {                      \
        short8 bfr = *(const short8*)(bp + ((co + 32 * ks) ^ sw));            \
        acc0 = __builtin_amdgcn_mfma_f32_32x32x16_bf16(A[kt * 4 + ks], bfr,   \
                                                       acc0, 0, 0, 0);        \
      }                                                                       \
    }                                                                         \
    {                                                                         \
      const int r  = th * 64 + 32 + l31 + kt;                                 \
      const int sw = (r & 7) << 4;                                            \
      const int co = hi * 16;                                                 \
      const char* bp = (CB) + r * 128;                                        \
      _Pragma("unroll") for (int ks = 0; ks < 4; ++ks) {                      \
        short8 bfr = *(const short8*)(bp + ((co + 32 * ks) ^ sw));            \
        acc1 = __builtin_amdgcn_mfma_f32_32x32x16_bf16(A[kt * 4 + ks], bfr,   \
                                                       acc1, 0, 0, 0);        \
      }                                                                       \
    }                                                                         \
  }

  // ---- prologue: A0 first (oldest in vmcnt queue), then stages s0,s1,s2 ----
  short8 aP[12], aQ[12];
  LOAD_A(aP, 0)
  __builtin_amdgcn_sched_barrier(0);
  {
    const char* gb0 = slab_base(xT, n, idx[v * KK + 0], tb);
    const char* gb1 = slab_base(xT, n, idx[v * KK + 1], tb);
    const char* gb2 = slab_base(xT, n, idx[v * KK + 2], tb);
#pragma unroll
    for (int s = 0; s < KK; ++s) {
      const char* gb = (s == 0) ? gb0 : ((s == 1) ? gb1 : gb2);
#pragma unroll
      for (int q = 0; q < 4; ++q) {
        int c = wave + q * 4;                // c in 0..15
        int Lb = c * 1024 + lane * 16;
        int g = Lb ^ (((Lb >> 7) & 7) << 4); // involution within 128B rows
        __builtin_amdgcn_global_load_lds(
            (const __attribute__((address_space(1))) void*)(gb + g),
            (__attribute__((address_space(3))) void*)(&xs[s][c * 1024]),
            16, 0, 0);
      }
      if (wave == 0) {                       // tail op: bytes 16384..17407
        int Lb = 16 * 1024 + lane * 16;
        int g = Lb ^ (((Lb >> 7) & 7) << 4);
        __builtin_amdgcn_global_load_lds(
            (const __attribute__((address_space(1))) void*)(gb + g),
            (__attribute__((address_space(3))) void*)(&xs[s][16 * 1024]),
            16, 0, 0);
      } else {                               // dummy: uniform 5 ops/slab/wave
        __builtin_amdgcn_global_load_lds(
            (const __attribute__((address_space(1))) void*)(gb + lane * 16),
            (__attribute__((address_space(3))) void*)(xs_dummy),
            16, 0, 0);
      }
      __builtin_amdgcn_sched_barrier(0);
    }
  }

  f32x16 acc0 = {}, acc1 = {};

  // ---- k = 0: wait own s0 (5 of 15 stage ops + A0 oldest) ----
  asm volatile("s_waitcnt vmcnt(10)" ::: "memory");
  __builtin_amdgcn_s_barrier();
  __builtin_amdgcn_sched_barrier(0);
  LOAD_A(aQ, 1)                              // prefetch A1 under k0 compute
  COMPUTE_K(xs[0], aP)

  // ---- k = 1: need s1; in-flight <= s2(5) + A1(12) ----
  asm volatile("s_waitcnt vmcnt(17)" ::: "memory");
  __builtin_amdgcn_s_barrier();
  __builtin_amdgcn_sched_barrier(0);
  COMPUTE_K(xs[1], aQ)

  // ---- k = 2: need s2; in-flight <= A1 leftovers (12) ----
  asm volatile("s_waitcnt vmcnt(12)" ::: "memory");
  __builtin_amdgcn_s_barrier();
  __builtin_amdgcn_sched_barrier(0);
  LOAD_A(aP, 2)                              // reuse aP (k0 MFMAs long done)
  COMPUTE_K(xs[2], aP)

#undef LOAD_A
#undef COMPUTE_K

  // epilogue: D col(t)=lane&31, row(o)=(reg&3)+8*(reg>>2)+4*(lane>>5)
  const float* bv = bias + v * COUTC;
#pragma unroll
  for (int s = 0; s < 2; ++s) {
    const f32x16& acc = s ? acc1 : acc0;
    const int t = tb + th * 64 + s * 32 + l31;
#pragma unroll
    for (int reg = 0; reg < 16; ++reg) {
      int o = os * 32 + 4 * hi + (reg & 3) + 8 * (reg >> 2);
      out[(((size_t)n * COUTC + o) * NV + v) * TLEN + t] = acc[reg] + bv[o];
    }
  }
}

// ================= FALLBACK PATH (round-1 fp32, known-good) =================
__global__ void prep_mask_kernel(const int* __restrict__ mask_raw,
                                 int* __restrict__ mask_out) {
  __shared__ int fmt;
  if (threadIdx.x == 0) {
    int ok = 1;
    for (int i = 0; i < 18; ++i) {
      int m = mask_raw[i];
      if (m != 0 && m != 1) ok = 0;
    }
    fmt = ok;
  }
  __syncthreads();
  int i = threadIdx.x;
  if (i < NV * KK) {
    int m;
    if (fmt) m = mask_raw[i];
    else     m = (((const unsigned char*)mask_raw)[i] != 0) ? 1 : 0;
    mask_out[i] = m;
  }
}

__global__ void prep_wt_kernel(const float* __restrict__ W,
                               float* __restrict__ Wt) {
  int v   = blockIdx.x / 9;
  int kkt = blockIdx.x % 9;
  const float* Wv = W + (size_t)v * COUTC * CINC * 9;
  float* dst = Wt + (size_t)blockIdx.x * (CINC * COUTC);
  for (int i = threadIdx.x; i < CINC * COUTC; i += 256) {
    int c = i >> 6;
    int o = i & 63;
    dst[i] = Wv[(o * CINC + c) * 9 + kkt];
  }
}

__global__ __launch_bounds__(256, 4) void lcn_main(
    const float* __restrict__ x, const float* __restrict__ Wt,
    const float* __restrict__ b, const int* __restrict__ idx,
    const int* __restrict__ maskn, float* __restrict__ out) {
  __shared__ float xsf[CINC][66];
  __shared__ float wsh[CINC][COUTC];
  const int tb  = blockIdx.x * 64;
  const int v   = blockIdx.y;
  const int n   = blockIdx.z;
  const int tid = threadIdx.x;
  const int t0  = tid & 63;
  const int og  = tid >> 6;
  float acc[16];
#pragma unroll
  for (int j = 0; j < 16; ++j) acc[j] = 0.f;
  for (int k = 0; k < KK; ++k) {
    const int vk = idx[v * KK + k];
    const int mk = maskn[v * KK + k];
    __syncthreads();
    for (int i = tid; i < CINC * 66; i += 256) {
      int c  = i / 66;
      int tt = i - c * 66;
      int gt = tb - 1 + tt;
      float val = 0.f;
      if (mk && gt >= 0 && gt < TLEN)
        val = x[(((size_t)n * CINC + c) * NV + vk) * TLEN + gt];
      xsf[c][tt] = val;
    }
    for (int kt = 0; kt < TKK; ++kt) {
      __syncthreads();
      const float4* src =
          (const float4*)(Wt + ((size_t)(v * KK + k) * TKK + kt) * (CINC * COUTC));
      for (int i = tid; i < CINC * COUTC / 4; i += 256)
        ((float4*)wsh)[i] = src[i];
      __syncthreads();
#pragma unroll 4
      for (int c = 0; c < CINC; ++c) {
        float xv = xsf[c][t0 + kt];
        const float4* wrow = (const float4*)&wsh[c][og * 16];
#pragma unroll
        for (int j4 = 0; j4 < 4; ++j4) {
          float4 wv = wrow[j4];
          acc[j4 * 4 + 0] = fmaf(wv.x, xv, acc[j4 * 4 + 0]);
          acc[j4 * 4 + 1] = fmaf(wv.y, xv, acc[j4 * 4 + 1]);
          acc[j4 * 4 + 2] = fmaf(wv.z, xv, acc[j4 * 4 + 2]);
          acc[j4 * 4 + 3] = fmaf(wv.w, xv, acc[j4 * 4 + 3]);
        }
      }
    }
  }
#pragma unroll
  for (int j = 0; j < 16; ++j) {
    int o = og * 16 + j;
    out[(((size_t)n * COUTC + o) * NV + v) * TLEN + tb + t0] =
        acc[j] + b[v * COUTC + o];
  }
}

extern "C" void kernel_launch(void* const* d_in, const int* in_sizes, int n_in,
                              void* d_out, int out_size, void* d_ws, size_t ws_size,
                              hipStream_t stream) {
  const float* x    = (const float*)d_in[0];
  const float* W    = (const float*)d_in[1];
  const float* b    = (const float*)d_in[2];
  const int*   idx  = (const int*)d_in[3];
  const void*  mask = (const void*)d_in[4];
  float* out = (float*)d_out;

  // ws: [0,512) maskn (fallback) | Wt3 1.84MB | xT padded 26.3MB | guard
  const size_t WT3_BYTES = (size_t)NV * 9 * 4096 * sizeof(__hip_bfloat16);
  const size_t XT_BYTES  = (size_t)NB * NV * XT_ROWS * CINC * sizeof(__hip_bfloat16);
  const size_t NEED      = 512 + WT3_BYTES + XT_BYTES + 2048;

  if (ws_size >= NEED) {
    __hip_bfloat16* Wt3 = (__hip_bfloat16*)((char*)d_ws + 512);
    __hip_bfloat16* xT  = (__hip_bfloat16*)((char*)d_ws + 512 + WT3_BYTES);
    hipLaunchKernelGGL(prep_all, dim3(NWT3BLK + 8 * NV * NB), dim3(256), 0,
                       stream, x, W, (const unsigned char*)mask, Wt3, xT);
    hipLaunchKernelGGL(lcn_mfma32, dim3(TLEN / 128, NB, NV), dim3(256), 0,
                       stream, xT, Wt3, b, idx, out);
  } else {
    int*   maskn = (int*)d_ws;
    float* Wt    = (float*)((char*)d_ws + 512);
    hipLaunchKernelGGL(prep_mask_kernel, dim3(1), dim3(128), 0, stream,
                       (const int*)mask, maskn);
    hipLaunchKernelGGL(prep_wt_kernel, dim3(NV * KK * TKK), dim3(256), 0, stream,
                       W, Wt);
    hipLaunchKernelGGL(lcn_main, dim3(TLEN / 64, NV, NB), dim3(256), 0, stream,
                       x, Wt, b, idx, maskn, out);
  }
}